// Round 1
// baseline (109.817 us; speedup 1.0000x reference)
//
#include <hip/hip_runtime.h>

// ECConv: out = relu(concat(nf[:8192], mean_seg(relu(EF@We+be).reshape(E,64,64) @ h_src)) @ Wn + bn)
// Sizes: E=65536, N_SRC=32768, N_DST=8192, EDGE_IN=32, NODE_IN=64, HIDDEN=64, cols=4096

typedef float f32x4 __attribute__((ext_vector_type(4)));
typedef __bf16 bf16x8 __attribute__((ext_vector_type(8)));
typedef __bf16 bf16x4 __attribute__((ext_vector_type(4)));

#define E_TOT   65536
#define NDST    8192
#define EP      264   // padded LDS row length (edges) for transposed h_src

// ---------------- pack W_e (fp32 [32][4096]) into MFMA-B fragment order, bf16 ----------------
// Tile T = d0*4 + ht covers GEMM cols n = (ht*16 + c)*64 + d0, c=0..15 (16 h at fixed d).
// B frag for mfma_f32_16x16x32_bf16: lane l holds B[k = (l>>4)*8 + j][col = l&15], j=0..7.
// Wp[(T*64 + l)*8 + j] = bf16(W_e[k*4096 + ncol]);  bp[T*16 + c] = b_e[ncol].
__global__ void pack_kernel(const float* __restrict__ We, const float* __restrict__ be,
                            __bf16* __restrict__ Wp, float* __restrict__ bp) {
  int tid = blockIdx.x * 256 + threadIdx.x;       // 16384 threads
  int T = tid >> 6, l = tid & 63;
  int d0 = T >> 2, ht = T & 3;
  int c = l & 15, kg = l >> 4;
  int ncol = (ht * 16 + c) * 64 + d0;
  bf16x8 v;
#pragma unroll
  for (int j = 0; j < 8; ++j) {
    int k = kg * 8 + j;
    v[j] = (__bf16)We[k * 4096 + ncol];
  }
  *reinterpret_cast<bf16x8*>(Wp + tid * 8) = v;
  if (l < 16) bp[T * 16 + l] = be[(ht * 16 + l) * 64 + d0];
}

// ---------------- per-dst edge counts ----------------
__global__ void cnt_kernel(const int* __restrict__ dst, float* __restrict__ cnt) {
  int e = blockIdx.x * 256 + threadIdx.x;
  if (e < E_TOT) unsafeAtomicAdd(&cnt[dst[e]], 1.0f);
}

// ---------------- main fused edge kernel ----------------
// Block: 256 threads = 4 waves; block covers 256 edges (wave w: 64 edges, 4 A-frags of 16).
// Per d0 (=NODE_IN dim), per ht: one MFMA per A-subgroup; epilogue: relu(C)*h_src -> acc.
// Lane's acc[as][ht][r] == m[edge = as*16 + (l>>4)*4 + r][h = ht*16 + (l&15)] (final, no reduce).
__global__ __launch_bounds__(256) void edge_kernel(
    const float* __restrict__ nf, const float* __restrict__ ef,
    const int* __restrict__ src, const int* __restrict__ dst,
    const __bf16* __restrict__ Wp, const float* __restrict__ bp,
    float* __restrict__ msum) {
  __shared__ __bf16 hs[64 * EP];   // transposed: hs[d][e_local], bf16, 33.8 KB
  const int t = threadIdx.x;
  const int eblk = blockIdx.x << 8;

  // stage h_src = nf[src[e]] transposed into LDS (thread t <-> edge t)
  {
    const int srow = src[eblk + t];
    const f32x4* nfr = (const f32x4*)(nf + (srow << 6));
#pragma unroll
    for (int q = 0; q < 16; ++q) {
      f32x4 v = nfr[q];
      hs[(q * 4 + 0) * EP + t] = (__bf16)v[0];
      hs[(q * 4 + 1) * EP + t] = (__bf16)v[1];
      hs[(q * 4 + 2) * EP + t] = (__bf16)v[2];
      hs[(q * 4 + 3) * EP + t] = (__bf16)v[3];
    }
  }

  const int w = t >> 6;      // wave id
  const int l = t & 63;      // lane
  const int c = l & 15;
  const int g = l >> 4;

  // A fragments from global EF (bf16 cvt in regs): lane holds A[row = c][k = g*8 + j]
  bf16x8 afr[4];
#pragma unroll
  for (int as = 0; as < 4; ++as) {
    const int e = eblk + w * 64 + as * 16 + c;
    const f32x4* p = (const f32x4*)(ef + (e << 5) + g * 8);
    f32x4 v0 = p[0], v1 = p[1];
    bf16x8 a;
    a[0] = (__bf16)v0[0]; a[1] = (__bf16)v0[1]; a[2] = (__bf16)v0[2]; a[3] = (__bf16)v0[3];
    a[4] = (__bf16)v1[0]; a[5] = (__bf16)v1[1]; a[6] = (__bf16)v1[2]; a[7] = (__bf16)v1[3];
    afr[as] = a;
  }

  __syncthreads();

  f32x4 acc[4][4];
#pragma unroll
  for (int i = 0; i < 4; ++i)
#pragma unroll
    for (int j = 0; j < 4; ++j) {
      acc[i][j][0] = 0.f; acc[i][j][1] = 0.f; acc[i][j][2] = 0.f; acc[i][j][3] = 0.f;
    }

  const bf16x8* WpV = (const bf16x8*)Wp;

#pragma unroll 2
  for (int d0 = 0; d0 < 64; ++d0) {
    bf16x8 bfr[4];
    f32x4 cb[4];
#pragma unroll
    for (int ht = 0; ht < 4; ++ht) {
      const int T = d0 * 4 + ht;
      bfr[ht] = WpV[T * 64 + l];
      const float bv = bp[T * 16 + c];
      cb[ht][0] = bv; cb[ht][1] = bv; cb[ht][2] = bv; cb[ht][3] = bv;
    }
#pragma unroll
    for (int as = 0; as < 4; ++as) {
      bf16x4 hv = *(const bf16x4*)&hs[d0 * EP + w * 64 + as * 16 + g * 4];
      const float hf0 = (float)hv[0], hf1 = (float)hv[1];
      const float hf2 = (float)hv[2], hf3 = (float)hv[3];
#pragma unroll
      for (int ht = 0; ht < 4; ++ht) {
        f32x4 tmp = __builtin_amdgcn_mfma_f32_16x16x32_bf16(afr[as], bfr[ht], cb[ht], 0, 0, 0);
        acc[as][ht][0] = fmaf(fmaxf(tmp[0], 0.f), hf0, acc[as][ht][0]);
        acc[as][ht][1] = fmaf(fmaxf(tmp[1], 0.f), hf1, acc[as][ht][1]);
        acc[as][ht][2] = fmaf(fmaxf(tmp[2], 0.f), hf2, acc[as][ht][2]);
        acc[as][ht][3] = fmaf(fmaxf(tmp[3], 0.f), hf3, acc[as][ht][3]);
      }
    }
  }

  // scatter m into msum via fp32 atomics (16 lanes = 16 consecutive h -> coalesced segments)
#pragma unroll
  for (int as = 0; as < 4; ++as) {
#pragma unroll
    for (int r = 0; r < 4; ++r) {
      const int e = eblk + w * 64 + as * 16 + g * 4 + r;
      const int dd = dst[e];
      float* base = msum + (dd << 6) + c;
      unsafeAtomicAdd(base + 0,  acc[as][0][r]);
      unsafeAtomicAdd(base + 16, acc[as][1][r]);
      unsafeAtomicAdd(base + 32, acc[as][2][r]);
      unsafeAtomicAdd(base + 48, acc[as][3][r]);
    }
  }
}

// ---------------- final: out = relu(concat(nf_row, msum_row/cnt) @ Wn + bn) ----------------
// One wave per dst row; lane = output h. Row-uniform loads become scalar loads.
__global__ void final_kernel(const float* __restrict__ nf, const float* __restrict__ msum,
                             const float* __restrict__ cnt, const float* __restrict__ Wn,
                             const float* __restrict__ bn, float* __restrict__ out) {
  const int row = blockIdx.x * 4 + (threadIdx.x >> 6);
  const int h = threadIdx.x & 63;
  const float cv = cnt[row];
  const float s = cv > 0.f ? 1.f / cv : 0.f;
  float acc = bn[h];
  const float* nfr = nf + (row << 6);
  const float* msr = msum + (row << 6);
#pragma unroll 8
  for (int k = 0; k < 64; ++k)
    acc = fmaf(nfr[k], Wn[k * 64 + h], acc);
#pragma unroll 8
  for (int k = 0; k < 64; ++k)
    acc = fmaf(msr[k] * s, Wn[(64 + k) * 64 + h], acc);
  out[(row << 6) + h] = fmaxf(acc, 0.f);
}

extern "C" void kernel_launch(void* const* d_in, const int* in_sizes, int n_in,
                              void* d_out, int out_size, void* d_ws, size_t ws_size,
                              hipStream_t stream) {
  const float* nf  = (const float*)d_in[0];
  const float* ef  = (const float*)d_in[1];
  const int*   src = (const int*)d_in[2];
  const int*   dst = (const int*)d_in[3];
  const float* We  = (const float*)d_in[4];
  const float* be  = (const float*)d_in[5];
  const float* Wn  = (const float*)d_in[6];
  const float* bn  = (const float*)d_in[7];
  float* out = (float*)d_out;

  char* ws = (char*)d_ws;
  float* msum = (float*)ws;                               // 8192*64*4 = 2097152 B
  float* cnt  = (float*)(ws + 2097152);                   // 8192*4    = 32768 B
  const size_t need = 2097152 + 32768 + 262144 + 16384;
  __bf16* Wp;
  float*  bp;
  if (ws_size >= need) {
    Wp = (__bf16*)(ws + 2097152 + 32768);                 // 256 KB
    bp = (float*)(ws + 2097152 + 32768 + 262144);         // 16 KB
  } else {
    // fallback: scratch Wp/bp in d_out (fully overwritten by final_kernel afterwards)
    Wp = (__bf16*)d_out;
    bp = (float*)((char*)d_out + 262144);
  }

  hipMemsetAsync(msum, 0, 2097152 + 32768, stream);
  pack_kernel<<<64, 256, 0, stream>>>(We, be, Wp, bp);
  cnt_kernel<<<E_TOT / 256, 256, 0, stream>>>(dst, cnt);
  edge_kernel<<<E_TOT / 256, 256, 0, stream>>>(nf, ef, src, dst, Wp, bp, msum);
  final_kernel<<<NDST / 4, 256, 0, stream>>>(nf, msum, cnt, Wn, bn, out);
}